// Round 18
// baseline (215.599 us; speedup 1.0000x reference)
//
#include <hip/hip_runtime.h>

#define NPIX    65536
#define D       64
#define KCODES  1024
#define PPW     16                 // pixels per wave
#define WPB     4                  // waves per block
#define PIXB    (PPW*WPB)          // 64 pixels per block
#define BLOCK   256
#define XPAD    68                 // xs row stride in floats
#define CAP     32                 // per-pixel candidate capacity
#define GFAC    0.036f             // certified gate factor (2B=0.0316 + slack)

// d_out layout (floats):
//   [0] loss | [1..4194305) quantized | [4194305] perplexity
//   [4194306..71303170) encodings | [71303170..) indices
#define QUANT_OFF 1
#define PERP_OFF  4194305
#define ENC_OFF   4194306u
#define IDX_OFF   71303170u

// d_ws layout:
//   [0..8) double loss_sum | [8..4104) int counts[1024]
//   [4104..8200) float se[1024] | [8200..8204) int semax_bits
//   [8320..139392) unsigned short ebf[1024*64]

typedef float f32x4 __attribute__((ext_vector_type(4)));
typedef short bf16x8 __attribute__((ext_vector_type(8)));

// RNE float->bf16 bits (deterministic, matches hardware RNE)
__device__ __forceinline__ unsigned short f2bf(float f) {
    unsigned u = __float_as_uint(f);
    return (unsigned short)((u + 0x7fffu + ((u >> 16) & 1u)) >> 16);
}

// numpy pairwise_sum (n=64): 8 accumulators stride-8, then
// ((r0+r1)+(r2+r3))+((r4+r5)+(r6+r7)); __f*_rn blocks contraction.
__global__ __launch_bounds__(256) void vq_init(const float* __restrict__ emb,
                                               double* __restrict__ loss_sum,
                                               int* __restrict__ counts,
                                               float* __restrict__ se,
                                               int* __restrict__ semax_bits,
                                               unsigned short* __restrict__ ebf) {
    int t = blockIdx.x * 256 + threadIdx.x;
    if (t == 0) *loss_sum = 0.0;
    if (t < KCODES) {
        counts[t] = 0;
        const float* e = emb + (size_t)t * D;
        float r[8];
        #pragma unroll
        for (int j = 0; j < 8; ++j) r[j] = __fmul_rn(e[j], e[j]);
        #pragma unroll
        for (int i = 8; i < D; i += 8)
            #pragma unroll
            for (int j = 0; j < 8; ++j)
                r[j] = __fadd_rn(r[j], __fmul_rn(e[i + j], e[i + j]));
        float X = __fadd_rn(__fadd_rn(r[0], r[1]), __fadd_rn(r[2], r[3]));
        float Y = __fadd_rn(__fadd_rn(r[4], r[5]), __fadd_rn(r[6], r[7]));
        float S = __fadd_rn(X, Y);
        se[t] = S;
        atomicMax(semax_bits, __float_as_int(S));   // positive floats: int cmp ok
        #pragma unroll
        for (int j = 0; j < D; ++j) ebf[(t << 6) + j] = f2bf(e[j]);
    }
}

// R18: wave-autonomous. One wave owns 16 pixels end-to-end; a single
// __syncthreads (block-shared sls stage) and otherwise ZERO barriers.
// Screen: MFMA 16x16x32, A=16 px rows, B=16 codes, C[px][code]
// (px=(lane>>4)*4+reg, code=lane&15 — m89-verified mapping, as R11-R17).
// Gate/append/exact-recheck math identical to the proven versions.
__global__ __launch_bounds__(256) void vq_main(const float* __restrict__ in,
                                               const float* __restrict__ emb,
                                               const float* __restrict__ se,
                                               const int* __restrict__ semax_bits,
                                               const unsigned short* __restrict__ ebf,
                                               float* __restrict__ out,
                                               double* __restrict__ loss_sum,
                                               int* __restrict__ counts) {
    __shared__ float xsw[WPB][PPW][XPAD];          // 17408 B (wave-local rows)
    __shared__ float sls[KCODES];                  // 4096 B (block-shared)
    __shared__ unsigned short listw[WPB][PPW][CAP];// 4096 B
    __shared__ int   cntw[WPB][PPW];
    __shared__ int   skw[WPB][PPW];
    __shared__ float sxw[WPB][PPW];

    const int tid  = threadIdx.x;
    const int lane = tid & 63;
    const int wid  = tid >> 6;                 // 0..3
    const int c0   = lane & 15;                // code-slot / pixel(P3) / col
    const int grp  = lane >> 4;                // 0..3
    const int n0w  = blockIdx.x * PIXB + wid * PPW;   // wave's 16 pixels
    const int b    = n0w >> 12;
    const int s0w  = n0w & 4095;

    // ---- stage: x tile (wave-local) + sls (block-shared, cooperative) ----
    {
        const float* base = in + ((size_t)b << 18) + s0w;
        #pragma unroll
        for (int i = 0; i < 16; ++i) {
            int d = i * 4 + grp;
            xsw[wid][c0][d] = base[((size_t)d << 12) + c0];
        }
        #pragma unroll
        for (int i = 0; i < 4; ++i)
            sls[tid + (i << 8)] = se[tid + (i << 8)];
    }
    __syncthreads();                           // the ONLY barrier

    // sx exact numpy chain (16 lanes, wave-local)
    if (lane < PPW) {
        cntw[wid][lane] = 0;
        float r[8];
        #pragma unroll
        for (int j = 0; j < 8; ++j) {
            float v = xsw[wid][lane][j];
            r[j] = __fmul_rn(v, v);
        }
        #pragma unroll
        for (int i = 8; i < D; i += 8)
            #pragma unroll
            for (int j = 0; j < 8; ++j) {
                float v = xsw[wid][lane][i + j];
                r[j] = __fadd_rn(r[j], __fmul_rn(v, v));
            }
        float X = __fadd_rn(__fadd_rn(r[0], r[1]), __fadd_rn(r[2], r[3]));
        float Y = __fadd_rn(__fadd_rn(r[4], r[5]), __fadd_rn(r[6], r[7]));
        sxw[wid][lane] = __fadd_rn(X, Y);
    }

    // A-fragments: row=c0 (pixel), k = ks*32 + grp*8 + j (8 VGPR total)
    bf16x8 af[2];
    #pragma unroll
    for (int ks = 0; ks < 2; ++ks) {
        const float* xp = &xsw[wid][c0][ks * 32 + (grp << 3)];
        bf16x8 v;
        #pragma unroll
        for (int j = 0; j < 8; ++j) v[j] = (short)f2bf(xp[j]);
        af[ks] = v;
    }
    const float semax = __int_as_float(*semax_bits);

    // ---------------- P1: screen, running min over 64 code-tiles --------
    float m[4] = {3.0e38f, 3.0e38f, 3.0e38f, 3.0e38f};
    for (int t = 0; t < 64; ++t) {
        f32x4 acc = (f32x4){0.f, 0.f, 0.f, 0.f};
        #pragma unroll
        for (int ks = 0; ks < 2; ++ks) {
            bf16x8 bf_ = *(const bf16x8*)(ebf + ((size_t)((t << 4) + c0) << 6)
                                          + ks * 32 + (grp << 3));
            acc = __builtin_amdgcn_mfma_f32_16x16x32_bf16(af[ks], bf_, acc, 0, 0, 0);
        }
        float sl = sls[(t << 4) + c0];
        #pragma unroll
        for (int r = 0; r < 4; ++r) {
            float sv = __fsub_rn(sl, __fmul_rn(2.0f, acc[r]));
            m[r] = fminf(m[r], sv);
        }
    }
    #pragma unroll
    for (int msk = 1; msk < 16; msk <<= 1)
        #pragma unroll
        for (int r = 0; r < 4; ++r)
            m[r] = fminf(m[r], __shfl_xor(m[r], msk));

    // certified gate, per lane for px = grp*4 + r (kept in registers)
    float gate[4];
    #pragma unroll
    for (int r = 0; r < 4; ++r)
        gate[r] = m[r] + GFAC * sqrtf(sxw[wid][(grp << 2) + r] * semax);
    asm volatile("" ::: "memory");

    // ---------------- P2: re-screen, append gated candidates ------------
    for (int t = 0; t < 64; ++t) {
        f32x4 acc = (f32x4){0.f, 0.f, 0.f, 0.f};
        #pragma unroll
        for (int ks = 0; ks < 2; ++ks) {
            bf16x8 bf_ = *(const bf16x8*)(ebf + ((size_t)((t << 4) + c0) << 6)
                                          + ks * 32 + (grp << 3));
            acc = __builtin_amdgcn_mfma_f32_16x16x32_bf16(af[ks], bf_, acc, 0, 0, 0);
        }
        float sl = sls[(t << 4) + c0];
        #pragma unroll
        for (int r = 0; r < 4; ++r) {
            float sv = __fsub_rn(sl, __fmul_rn(2.0f, acc[r]));
            if (sv <= gate[r]) {
                int px = (grp << 2) + r;
                int slot = atomicAdd(&cntw[wid][px], 1);
                if (slot < CAP) listw[wid][px][slot] = (unsigned short)((t << 4) + c0);
            }
        }
    }
    asm volatile("" ::: "memory");

    // ---------------- P3: exact numpy-chain recheck (4 lanes per px) ----
    {
        const int px = c0, sub = grp;
        const int cn = cntw[wid][px];
        float bv = 3.0e38f;
        int   bk = 0x7fffffff;
        if (cn > CAP || cn == 0) {
            for (int k = sub; k < KCODES; k += 4) {
                const float* er = emb + ((size_t)k << 6);
                float mm = 0.f;
                #pragma unroll
                for (int d = 0; d < D; ++d) mm = fmaf(xsw[wid][px][d], er[d], mm);
                float sv = __fsub_rn(__fadd_rn(sxw[wid][px], sls[k]), __fmul_rn(2.0f, mm));
                if (sv < bv || (sv == bv && k < bk)) { bv = sv; bk = k; }
            }
        } else {
            for (int i = sub; i < cn; i += 4) {
                int k = listw[wid][px][i];
                const float* er = emb + ((size_t)k << 6);
                float mm = 0.f;
                #pragma unroll
                for (int d = 0; d < D; ++d) mm = fmaf(xsw[wid][px][d], er[d], mm);
                float sv = __fsub_rn(__fadd_rn(sxw[wid][px], sls[k]), __fmul_rn(2.0f, mm));
                if (sv < bv || (sv == bv && k < bk)) { bv = sv; bk = k; }
            }
        }
        #pragma unroll
        for (int msk = 16; msk < 64; msk <<= 1) {
            float ov = __shfl_xor(bv, msk);
            int   ok = __shfl_xor(bk, msk);
            if (ov < bv || (ov == bv && ok < bk)) { bv = ov; bk = ok; }
        }
        if (sub == 0) {
            skw[wid][px] = bk;
            atomicAdd(&counts[bk], 1);
            out[IDX_OFF + (unsigned)(n0w + px)] = (float)bk;
        }
    }
    asm volatile("" ::: "memory");

    // ---- quantized (NCHW) + mse: lane covers (px=c0, d = i*4+grp) ------
    {
        float* qbase = out + QUANT_OFF + ((size_t)b << 18) + s0w;
        const float* eq = emb + ((size_t)skw[wid][c0] << 6);
        float mse = 0.f;
        #pragma unroll
        for (int i = 0; i < 16; ++i) {
            int d = i * 4 + grp;
            float q = eq[d];
            qbase[((size_t)d << 12) + c0] = q;
            float df = q - xsw[wid][c0][d];
            mse = fmaf(df, df, mse);
        }
        #pragma unroll
        for (int off = 32; off; off >>= 1) mse += __shfl_down(mse, off);
        if (lane == 0) atomicAdd(loss_sum, (double)mse);
    }

    // ---- enc: this wave's 16 rows = 64 KB contiguous, single pass ------
    {
        float4* dst4 = (float4*)(out + ENC_OFF + (size_t)n0w * KCODES + 2);
        for (int i = lane; i < 4095; i += 64) {
            int flat = (i << 2) + 2;
            int r0 = flat >> 10;
            int r1 = (flat + 3) >> 10;        // row crossing only at c==1022
            int k0 = skw[wid][r0];
            int k1 = skw[wid][r1];
            int c  = flat & 1023;
            float4 v;
            v.x = (c == k0) ? 1.f : 0.f;
            v.y = (c + 1 == k0) ? 1.f : 0.f;
            v.z = (((flat + 2) & 1023) == k1) ? 1.f : 0.f;
            v.w = (((flat + 3) & 1023) == k1) ? 1.f : 0.f;
            dst4[i] = v;
        }
        if (lane == 0) {
            float2* dh = (float2*)(out + ENC_OFF + (size_t)n0w * KCODES);
            int kh = skw[wid][0];
            float2 h2; h2.x = (kh == 0) ? 1.f : 0.f; h2.y = (kh == 1) ? 1.f : 0.f;
            *dh = h2;
            float2* dt = (float2*)(out + ENC_OFF + (size_t)n0w * KCODES + 16382);
            int kt = skw[wid][15];
            float2 t2; t2.x = (kt == 1022) ? 1.f : 0.f; t2.y = (kt == 1023) ? 1.f : 0.f;
            *dt = t2;
        }
    }
}

__global__ __launch_bounds__(256) void vq_fin(const double* __restrict__ loss_sum,
                                              const int* __restrict__ counts,
                                              float* __restrict__ out) {
    __shared__ double red[256];
    int t = threadIdx.x;
    double ent = 0.0;
    for (int k = t; k < KCODES; k += 256) {
        double p = (double)counts[k] / 65536.0;
        ent -= p * log(p + 1e-10);
    }
    red[t] = ent;
    __syncthreads();
    for (int o = 128; o; o >>= 1) {
        if (t < o) red[t] += red[t + o];
        __syncthreads();
    }
    if (t == 0) {
        out[PERP_OFF] = (float)exp(red[0]);
        out[0] = (float)(1.25 * (*loss_sum) / 4194304.0);
    }
}

extern "C" void kernel_launch(void* const* d_in, const int* in_sizes, int n_in,
                              void* d_out, int out_size, void* d_ws, size_t ws_size,
                              hipStream_t stream) {
    const float* in  = (const float*)d_in[0];
    const float* emb = (const float*)d_in[1];
    float* out = (float*)d_out;

    double*         loss_sum   = (double*)d_ws;
    int*            counts     = (int*)((char*)d_ws + 8);
    float*          se         = (float*)((char*)d_ws + 4104);
    int*            semax_bits = (int*)((char*)d_ws + 8200);
    unsigned short* ebf        = (unsigned short*)((char*)d_ws + 8320);

    vq_init<<<4, 256, 0, stream>>>(emb, loss_sum, counts, se, semax_bits, ebf);
    vq_main<<<NPIX / PIXB, BLOCK, 0, stream>>>(in, emb, se, semax_bits, ebf,
                                               out, loss_sum, counts);
    vq_fin<<<1, 256, 0, stream>>>(loss_sum, counts, out);
}

// Round 19
// 162.850 us; speedup vs baseline: 1.3239x; 1.3239x over previous
//
#include <hip/hip_runtime.h>

#define NPIX    65536
#define D       64
#define KCODES  1024
#define PIXB    64
#define BLOCK   512
#define XPAD    68                 // xs (fp32) row stride in floats
#define CAP     64                 // per-pixel candidate list capacity
#define GFAC    0.036f             // certified gate factor (2B=0.0316 + slack)

// d_out layout (floats):
//   [0] loss | [1..4194305) quantized | [4194305] perplexity
//   [4194306..71303170) encodings | [71303170..) indices
#define QUANT_OFF 1
#define PERP_OFF  4194305
#define ENC_OFF   4194306u
#define IDX_OFF   71303170u

typedef float f32x4 __attribute__((ext_vector_type(4)));
typedef short bf16x8 __attribute__((ext_vector_type(8)));

// RNE float->bf16 bits (deterministic, matches hardware RNE)
__device__ __forceinline__ unsigned short f2bf(float f) {
    unsigned u = __float_as_uint(f);
    return (unsigned short)((u + 0x7fffu + ((u >> 16) & 1u)) >> 16);
}
__device__ __forceinline__ bf16x8 pack8(const float* p) {
    bf16x8 v;
    v[0] = (short)f2bf(p[0]); v[1] = (short)f2bf(p[1]);
    v[2] = (short)f2bf(p[2]); v[3] = (short)f2bf(p[3]);
    v[4] = (short)f2bf(p[4]); v[5] = (short)f2bf(p[5]);
    v[6] = (short)f2bf(p[6]); v[7] = (short)f2bf(p[7]);
    return v;
}

// numpy pairwise_sum (n=64): 8 accumulators stride-8, then
// ((r0+r1)+(r2+r3))+((r4+r5)+(r6+r7)); __f*_rn blocks contraction.
__global__ __launch_bounds__(256) void vq_init(const float* __restrict__ emb,
                                               double* __restrict__ loss_sum,
                                               int* __restrict__ counts,
                                               float* __restrict__ se) {
    int t = blockIdx.x * 256 + threadIdx.x;
    if (t == 0) *loss_sum = 0.0;
    if (t < KCODES) {
        counts[t] = 0;
        const float* e = emb + (size_t)t * D;
        float r[8];
        #pragma unroll
        for (int j = 0; j < 8; ++j) r[j] = __fmul_rn(e[j], e[j]);
        #pragma unroll
        for (int i = 8; i < D; i += 8)
            #pragma unroll
            for (int j = 0; j < 8; ++j)
                r[j] = __fadd_rn(r[j], __fmul_rn(e[i + j], e[i + j]));
        float X = __fadd_rn(__fadd_rn(r[0], r[1]), __fadd_rn(r[2], r[3]));
        float Y = __fadd_rn(__fadd_rn(r[4], r[5]), __fadd_rn(r[6], r[7]));
        se[t] = __fadd_rn(X, Y);
    }
}

// R19 vq_main = champion R11, byte-identical, MINUS the enc epilogue
// (enc moved to the grid-striped writer below).
__global__ __launch_bounds__(512) void vq_main(const float* __restrict__ in,
                                               const float* __restrict__ emb,
                                               const float* __restrict__ se,
                                               float* __restrict__ out,
                                               double* __restrict__ loss_sum,
                                               int* __restrict__ counts) {
    __shared__ float xs[PIXB][XPAD];          // 17408 B (fp32, exact math)
    __shared__ float sls[KCODES];             // 4096 B (fp32 se, = numpy fl)
    __shared__ float wmin[8][PIXB];           // per-wave per-pixel screen min
    __shared__ float gate[PIXB];
    __shared__ float sxs[PIXB];
    __shared__ float smx[PIXB];
    __shared__ float semaxsq;
    __shared__ int   cnt[PIXB];
    __shared__ unsigned short list[PIXB][CAP];
    __shared__ int   skfin[PIXB];

    const int tid  = threadIdx.x;
    const int lane = tid & 63;
    const int wid  = tid >> 6;                // 0..7
    const int n0   = blockIdx.x * PIXB;
    const int b    = n0 >> 12;
    const int s0   = n0 & 4095;

    // stage x tile (transpose) + se into LDS
    {
        const float* base = in + ((size_t)b << 18) + s0;
        #pragma unroll
        for (int i = 0; i < 8; ++i) {
            int d = wid + (i << 3);
            xs[lane][d] = base[((size_t)d << 12) + lane];
        }
        sls[tid] = se[tid];
        sls[tid + 512] = se[tid + 512];
    }
    __syncthreads();

    // tid<64: exact numpy pairwise sx per pixel + partial max of se
    if (tid < PIXB) {
        float r[8];
        #pragma unroll
        for (int j = 0; j < 8; ++j) {
            float v = xs[tid][j];
            r[j] = __fmul_rn(v, v);
        }
        #pragma unroll
        for (int i = 8; i < D; i += 8)
            #pragma unroll
            for (int j = 0; j < 8; ++j) {
                float v = xs[tid][i + j];
                r[j] = __fadd_rn(r[j], __fmul_rn(v, v));
            }
        float X = __fadd_rn(__fadd_rn(r[0], r[1]), __fadd_rn(r[2], r[3]));
        float Y = __fadd_rn(__fadd_rn(r[4], r[5]), __fadd_rn(r[6], r[7]));
        sxs[tid] = __fadd_rn(X, Y);
        float mx = sls[tid << 4];
        #pragma unroll
        for (int j = 1; j < 16; ++j) mx = fmaxf(mx, sls[(tid << 4) + j]);
        smx[tid] = mx;
    }

    const int wbase = wid * 128;
    const int arow  = lane & 15;              // A row / B col within tile
    const int kgrp  = (lane >> 4) << 3;       // k-offset of this lane's 8 elems
    const int rbase = (lane >> 4) << 2;       // D row base

    // ---------------- P1: screen, per-wave per-pixel min ----------------
    float mreg[4][4];
    #pragma unroll
    for (int pt = 0; pt < 4; ++pt)
        #pragma unroll
        for (int r = 0; r < 4; ++r) mreg[pt][r] = 3.0e38f;

    #pragma unroll
    for (int s = 0; s < 2; ++s) {
        const int cbase = wbase + s * 64;
        f32x4 acc[4][4];
        #pragma unroll
        for (int pt = 0; pt < 4; ++pt)
            #pragma unroll
            for (int kt = 0; kt < 4; ++kt) acc[pt][kt] = (f32x4){0.f, 0.f, 0.f, 0.f};
        #pragma unroll
        for (int ks = 0; ks < 2; ++ks) {
            bf16x8 af[4];
            #pragma unroll
            for (int pt = 0; pt < 4; ++pt)
                af[pt] = pack8(&xs[pt * 16 + arow][ks * 32 + kgrp]);
            #pragma unroll
            for (int kt = 0; kt < 4; ++kt) {
                int code = cbase + kt * 16 + arow;
                bf16x8 bf_ = pack8(emb + ((size_t)code << 6) + ks * 32 + kgrp);
                #pragma unroll
                for (int pt = 0; pt < 4; ++pt)
                    acc[pt][kt] = __builtin_amdgcn_mfma_f32_16x16x32_bf16(
                        af[pt], bf_, acc[pt][kt], 0, 0, 0);
            }
        }
        #pragma unroll
        for (int pt = 0; pt < 4; ++pt)
            #pragma unroll
            for (int kt = 0; kt < 4; ++kt) {
                int code = cbase + kt * 16 + arow;
                #pragma unroll
                for (int r = 0; r < 4; ++r) {
                    float sv = __fsub_rn(sls[code], __fmul_rn(2.0f, acc[pt][kt][r]));
                    mreg[pt][r] = fminf(mreg[pt][r], sv);
                }
            }
    }
    #pragma unroll
    for (int m = 1; m < 16; m <<= 1)
        #pragma unroll
        for (int pt = 0; pt < 4; ++pt)
            #pragma unroll
            for (int r = 0; r < 4; ++r)
                mreg[pt][r] = fminf(mreg[pt][r], __shfl_xor(mreg[pt][r], m));
    if (arow == 0) {
        #pragma unroll
        for (int pt = 0; pt < 4; ++pt)
            #pragma unroll
            for (int r = 0; r < 4; ++r)
                wmin[wid][pt * 16 + rbase + r] = mreg[pt][r];
    }
    __syncthreads();

    if (tid == 0) {
        float mx = smx[0];
        #pragma unroll
        for (int j = 1; j < PIXB; ++j) mx = fmaxf(mx, smx[j]);
        semaxsq = mx;
    }
    __syncthreads();

    if (tid < PIXB) {
        float gm = wmin[0][tid];
        #pragma unroll
        for (int w = 1; w < 8; ++w) gm = fminf(gm, wmin[w][tid]);
        gate[tid] = gm + GFAC * sqrtf(sxs[tid] * semaxsq);
        cnt[tid] = 0;
    }
    __syncthreads();

    // ---------------- P2: recompute screen, append gated candidates -----
    #pragma unroll
    for (int s = 0; s < 2; ++s) {
        const int cbase = wbase + s * 64;
        f32x4 acc[4][4];
        #pragma unroll
        for (int pt = 0; pt < 4; ++pt)
            #pragma unroll
            for (int kt = 0; kt < 4; ++kt) acc[pt][kt] = (f32x4){0.f, 0.f, 0.f, 0.f};
        #pragma unroll
        for (int ks = 0; ks < 2; ++ks) {
            bf16x8 af[4];
            #pragma unroll
            for (int pt = 0; pt < 4; ++pt)
                af[pt] = pack8(&xs[pt * 16 + arow][ks * 32 + kgrp]);
            #pragma unroll
            for (int kt = 0; kt < 4; ++kt) {
                int code = cbase + kt * 16 + arow;
                bf16x8 bf_ = pack8(emb + ((size_t)code << 6) + ks * 32 + kgrp);
                #pragma unroll
                for (int pt = 0; pt < 4; ++pt)
                    acc[pt][kt] = __builtin_amdgcn_mfma_f32_16x16x32_bf16(
                        af[pt], bf_, acc[pt][kt], 0, 0, 0);
            }
        }
        #pragma unroll
        for (int pt = 0; pt < 4; ++pt)
            #pragma unroll
            for (int kt = 0; kt < 4; ++kt) {
                int code = cbase + kt * 16 + arow;
                #pragma unroll
                for (int r = 0; r < 4; ++r) {
                    float sv = __fsub_rn(sls[code], __fmul_rn(2.0f, acc[pt][kt][r]));
                    int px = pt * 16 + rbase + r;
                    if (sv <= gate[px]) {
                        int slot = atomicAdd(&cnt[px], 1);
                        if (slot < CAP) list[px][slot] = (unsigned short)code;
                    }
                }
            }
    }
    __syncthreads();

    // ---------------- P3: exact numpy-chain recheck over gated set ------
    {
        const int px = tid >> 3, c0 = tid & 7;
        const int cn = cnt[px];
        float bv = 3.0e38f;
        int   bk = 0x7fffffff;
        if (cn > CAP) {
            // overflow fallback: exact full scan (correctness-preserving)
            for (int k = c0; k < KCODES; k += 8) {
                const float* er = emb + ((size_t)k << 6);
                float m = 0.f;
                #pragma unroll
                for (int d = 0; d < D; ++d) m = fmaf(xs[px][d], er[d], m);
                float sv = __fsub_rn(__fadd_rn(sxs[px], sls[k]), __fmul_rn(2.0f, m));
                if (sv < bv || (sv == bv && k < bk)) { bv = sv; bk = k; }
            }
        } else {
            for (int i = c0; i < cn; i += 8) {
                int k = list[px][i];
                const float* er = emb + ((size_t)k << 6);
                float m = 0.f;
                #pragma unroll
                for (int d = 0; d < D; ++d) m = fmaf(xs[px][d], er[d], m);
                float sv = __fsub_rn(__fadd_rn(sxs[px], sls[k]), __fmul_rn(2.0f, m));
                if (sv < bv || (sv == bv && k < bk)) { bv = sv; bk = k; }
            }
        }
        #pragma unroll
        for (int m = 4; m; m >>= 1) {
            float ov = __shfl_xor(bv, m);
            int   ok = __shfl_xor(bk, m);
            if (ov < bv || (ov == bv && ok < bk)) { bv = ov; bk = ok; }
        }
        if (c0 == 0) {
            skfin[px] = bk;
            atomicAdd(&counts[bk], 1);
            out[IDX_OFF + (unsigned)(n0 + px)] = (float)bk;
        }
    }
    __syncthreads();

    // ---------------- epilogue (identical numerics to R11) ---------------
    if (tid < PIXB) {
        int bk2 = skfin[tid];
        const float* eq = emb + ((size_t)bk2 << 6);
        float* qout = out + QUANT_OFF + ((size_t)b << 18) + s0 + tid;
        float mse = 0.f;
        #pragma unroll
        for (int d = 0; d < D; ++d) {
            float q = eq[d];
            qout[(size_t)d << 12] = q;
            float df = q - xs[tid][d];
            mse = fmaf(df, df, mse);
        }
        #pragma unroll
        for (int off = 32; off; off >>= 1) mse += __shfl_down(mse, off);
        if (tid == 0) atomicAdd(loss_sum, (double)mse);
    }
    // (enc write removed — handled by grid-striped vq_enc below)
}

// Grid-striped one-hot writer: fillBuffer-style access pattern. Consecutive
// threads chip-wide write consecutive float4s -> one dense moving address
// window (DRAM page friendly), instead of 1024 interleaved per-block streams.
// Values derived from idx rows (broadcast L2 loads, reused 256x per row).
__global__ __launch_bounds__(256) void vq_enc(float* __restrict__ out) {
    const int NF4 = 16777215;                 // f4 slots in [ENC_OFF+2, ...)
    const int gsz = gridDim.x * 256;
    float4* dst = (float4*)(out + ENC_OFF + 2);
    for (int g = blockIdx.x * 256 + threadIdx.x; g < NF4; g += gsz) {
        int flat = (g << 2) + 2;              // 2 .. 67108858, fits int
        int r0 = flat >> 10;
        int r1 = (flat + 3) >> 10;            // row crossing only at c==1022
        int k0 = (int)out[IDX_OFF + (unsigned)r0];
        int k1 = (int)out[IDX_OFF + (unsigned)r1];
        int c  = flat & 1023;
        float4 v;
        v.x = (c == k0) ? 1.f : 0.f;
        v.y = (c + 1 == k0) ? 1.f : 0.f;
        v.z = (((flat + 2) & 1023) == k1) ? 1.f : 0.f;
        v.w = (((flat + 3) & 1023) == k1) ? 1.f : 0.f;
        dst[g] = v;
    }
    if (blockIdx.x == 0 && threadIdx.x == 0) {
        int kh = (int)out[IDX_OFF];
        float2 h2; h2.x = (kh == 0) ? 1.f : 0.f; h2.y = (kh == 1) ? 1.f : 0.f;
        *(float2*)(out + ENC_OFF) = h2;
        int kt = (int)out[IDX_OFF + 65535u];
        float2 t2; t2.x = (kt == 1022) ? 1.f : 0.f; t2.y = (kt == 1023) ? 1.f : 0.f;
        *(float2*)(out + ENC_OFF + 67108862u) = t2;
    }
}

__global__ __launch_bounds__(256) void vq_fin(const double* __restrict__ loss_sum,
                                              const int* __restrict__ counts,
                                              float* __restrict__ out) {
    __shared__ double red[256];
    int t = threadIdx.x;
    double ent = 0.0;
    for (int k = t; k < KCODES; k += 256) {
        double p = (double)counts[k] / 65536.0;
        ent -= p * log(p + 1e-10);
    }
    red[t] = ent;
    __syncthreads();
    for (int o = 128; o; o >>= 1) {
        if (t < o) red[t] += red[t + o];
        __syncthreads();
    }
    if (t == 0) {
        out[PERP_OFF] = (float)exp(red[0]);
        out[0] = (float)(1.25 * (*loss_sum) / 4194304.0);
    }
}

extern "C" void kernel_launch(void* const* d_in, const int* in_sizes, int n_in,
                              void* d_out, int out_size, void* d_ws, size_t ws_size,
                              hipStream_t stream) {
    const float* in  = (const float*)d_in[0];
    const float* emb = (const float*)d_in[1];
    float* out = (float*)d_out;

    double* loss_sum = (double*)d_ws;
    int*    counts   = (int*)((char*)d_ws + 8);
    float*  se       = (float*)((char*)d_ws + 8 + 4096);

    vq_init<<<4, 256, 0, stream>>>(emb, loss_sum, counts, se);
    vq_main<<<NPIX / PIXB, BLOCK, 0, stream>>>(in, emb, se, out, loss_sum, counts);
    vq_enc<<<4096, 256, 0, stream>>>(out);
    vq_fin<<<1, 256, 0, stream>>>(loss_sum, counts, out);
}